// Round 1
// baseline (36301.492 us; speedup 1.0000x reference)
//
#include <hip/hip_runtime.h>
#include <math.h>

#define NHD 850
#define LDW 1700
#define SSZ (256 * 850)          // one state matrix, floats
#define WSTRIDE (850 * 1700)     // one edge weight, floats

#define BM 64
#define BN 64
#define BK 32
#define APAD 4                   // keep LDS rows 16B-aligned (68 floats = 272B)

struct EdgeA {
  const float* Ax;   // A element for k < 850
  const float* Ah;   // A element for k >= 850 (concat case)
  const float* W;    // [K x 1700] row-major
  const float* pred; // s_prev for the highway gate epilogue [256 x 850]
  float* out;        // [256 x 850]
  int K;             // 850 or 1700
  int act;           // 0 tanh, 1 relu, 2 sigmoid, 3 identity
};
struct EdgeB3 { EdgeA e[3]; };

__device__ __forceinline__ float actf(int a, float x) {
  switch (a) {
    case 0: return tanhf(x);
    case 1: return fmaxf(x, 0.0f);
    case 2: return 1.0f / (1.0f + expf(-x));
    default: return x;
  }
}

#define FMAROW(accR, avc, bv)                 \
  accR.x = fmaf(avc, bv.x, accR.x);           \
  accR.y = fmaf(avc, bv.y, accR.y);           \
  accR.z = fmaf(avc, bv.z, accR.z);           \
  accR.w = fmaf(avc, bv.w, accR.w);

// C[256 x 2*850] = A[256 x K] @ W[K x 1700], fused highway-gate epilogue:
// out = p + sigmoid(c) * (act(h) - p), c = cols [0,850), h = cols [850,1700)
__global__ __launch_bounds__(256) void k_gemm_gate(EdgeB3 batch) {
  const EdgeA ea = batch.e[blockIdx.z];
  const float* __restrict__ Ax = ea.Ax;
  const float* __restrict__ Ah = ea.Ah;
  const float* __restrict__ W  = ea.W;
  const int K    = ea.K;
  const int row0 = blockIdx.x * BM;
  const int col0 = blockIdx.y * BN;

  __shared__ float As[BK][BM + APAD];
  __shared__ float Bc[BK][BN];
  __shared__ float Bh[BK][BN];

  const int tid = threadIdx.x;
  const int am = tid >> 2;            // 0..63  (A row within tile)
  const int ak = (tid & 3) << 3;      // 0,8,16,24 (A k within tile)
  const int wk = tid >> 3;            // 0..31  (W k within tile)
  const int wn = (tid & 7) << 3;      // 0..56  (W col within tile)
  const int ty = tid >> 4;            // 0..15  compute row group
  const int tx = tid & 15;            // 0..15  compute col group

  float4 ac[4], ahh[4];
  #pragma unroll
  for (int i = 0; i < 4; ++i) {
    ac[i]  = make_float4(0.f, 0.f, 0.f, 0.f);
    ahh[i] = make_float4(0.f, 0.f, 0.f, 0.f);
  }

  for (int kt = 0; kt < K; kt += BK) {
    // ---- stage A tile (transposed): As[k][m]; rows are only 8B-aligned -> float2
    {
      const int r  = row0 + am;
      const int kb = kt + ak;
      if (kb + 7 < 850) {
        const float2* p = (const float2*)(Ax + (size_t)r * NHD + kb);
        float2 v0 = p[0], v1 = p[1], v2 = p[2], v3 = p[3];
        As[ak+0][am] = v0.x; As[ak+1][am] = v0.y;
        As[ak+2][am] = v1.x; As[ak+3][am] = v1.y;
        As[ak+4][am] = v2.x; As[ak+5][am] = v2.y;
        As[ak+6][am] = v3.x; As[ak+7][am] = v3.y;
      } else if (kb >= 850 && kb + 7 < K) {
        const float2* p = (const float2*)(Ah + (size_t)r * NHD + (kb - 850));
        float2 v0 = p[0], v1 = p[1], v2 = p[2], v3 = p[3];
        As[ak+0][am] = v0.x; As[ak+1][am] = v0.y;
        As[ak+2][am] = v1.x; As[ak+3][am] = v1.y;
        As[ak+4][am] = v2.x; As[ak+5][am] = v2.y;
        As[ak+6][am] = v3.x; As[ak+7][am] = v3.y;
      } else {
        #pragma unroll
        for (int i = 0; i < 8; ++i) {
          int k = kb + i;
          float v = 0.f;
          if (k < K) v = (k < 850) ? Ax[(size_t)r * NHD + k]
                                   : Ah[(size_t)r * NHD + (k - 850)];
          As[ak + i][am] = v;
        }
      }
    }
    // ---- stage W tiles (c half and h half); h half is 8B-aligned -> float2
    {
      const int k = kt + wk;
      const float* wr = W + (size_t)k * LDW;
      if (k < K && col0 + BN <= NHD) {
        const float2* pc = (const float2*)(wr + col0 + wn);
        const float2* ph = (const float2*)(wr + NHD + col0 + wn);
        float2 c0 = pc[0], c1 = pc[1], c2 = pc[2], c3 = pc[3];
        float2 h0 = ph[0], h1 = ph[1], h2 = ph[2], h3 = ph[3];
        *(float2*)&Bc[wk][wn + 0] = c0; *(float2*)&Bc[wk][wn + 2] = c1;
        *(float2*)&Bc[wk][wn + 4] = c2; *(float2*)&Bc[wk][wn + 6] = c3;
        *(float2*)&Bh[wk][wn + 0] = h0; *(float2*)&Bh[wk][wn + 2] = h1;
        *(float2*)&Bh[wk][wn + 4] = h2; *(float2*)&Bh[wk][wn + 6] = h3;
      } else {
        #pragma unroll
        for (int i = 0; i < 8; ++i) {
          int j = col0 + wn + i;
          bool ok = (k < K) && (j < NHD);
          Bc[wk][wn + i] = ok ? wr[j] : 0.f;
          Bh[wk][wn + i] = ok ? wr[NHD + j] : 0.f;
        }
      }
    }
    __syncthreads();

    #pragma unroll
    for (int kk = 0; kk < BK; ++kk) {
      float4 av = *(const float4*)&As[kk][ty << 2];
      float4 bc = *(const float4*)&Bc[kk][tx << 2];
      float4 bh = *(const float4*)&Bh[kk][tx << 2];
      FMAROW(ac[0],  av.x, bc); FMAROW(ac[1],  av.y, bc);
      FMAROW(ac[2],  av.z, bc); FMAROW(ac[3],  av.w, bc);
      FMAROW(ahh[0], av.x, bh); FMAROW(ahh[1], av.y, bh);
      FMAROW(ahh[2], av.z, bh); FMAROW(ahh[3], av.w, bh);
    }
    __syncthreads();
  }

  // ---- fused highway-gate epilogue
  const float* __restrict__ P = ea.pred;
  float* __restrict__ O = ea.out;
  const int act = ea.act;
  #pragma unroll
  for (int i = 0; i < 4; ++i) {
    const int r = row0 + (ty << 2) + i;
    float cc[4] = { ac[i].x,  ac[i].y,  ac[i].z,  ac[i].w  };
    float hh[4] = { ahh[i].x, ahh[i].y, ahh[i].z, ahh[i].w };
    #pragma unroll
    for (int j = 0; j < 4; ++j) {
      const int jc = col0 + (tx << 2) + j;
      if (jc < NHD) {
        float p = P[(size_t)r * NHD + jc];
        float g = 1.0f / (1.0f + expf(-cc[j]));
        float a = actf(act, hh[j]);
        O[(size_t)r * NHD + jc] = p + g * (a - p);
      }
    }
  }
}

// mean of s1..s8 -> out_t (and optionally the final-hidden tail slot)
__global__ __launch_bounds__(256) void k_mean8(
    const float* __restrict__ s1, const float* __restrict__ s2,
    const float* __restrict__ s3, const float* __restrict__ s4,
    const float* __restrict__ s5, const float* __restrict__ s6,
    const float* __restrict__ s7, const float* __restrict__ s8,
    float* __restrict__ o1, float* o2) {
  int i = blockIdx.x * blockDim.x + threadIdx.x;
  if (i >= SSZ / 4) return;
  float4 v1 = ((const float4*)s1)[i], v2 = ((const float4*)s2)[i];
  float4 v3 = ((const float4*)s3)[i], v4 = ((const float4*)s4)[i];
  float4 v5 = ((const float4*)s5)[i], v6 = ((const float4*)s6)[i];
  float4 v7 = ((const float4*)s7)[i], v8 = ((const float4*)s8)[i];
  float4 r;
  r.x = (v1.x + v2.x + v3.x + v4.x + v5.x + v6.x + v7.x + v8.x) * 0.125f;
  r.y = (v1.y + v2.y + v3.y + v4.y + v5.y + v6.y + v7.y + v8.y) * 0.125f;
  r.z = (v1.z + v2.z + v3.z + v4.z + v5.z + v6.z + v7.z + v8.z) * 0.125f;
  r.w = (v1.w + v2.w + v3.w + v4.w + v5.w + v6.w + v7.w + v8.w) * 0.125f;
  ((float4*)o1)[i] = r;
  if (o2) ((float4*)o2)[i] = r;
}

extern "C" void kernel_launch(void* const* d_in, const int* in_sizes, int n_in,
                              void* d_out, int out_size, void* d_ws, size_t ws_size,
                              hipStream_t stream) {
  (void)in_sizes; (void)n_in; (void)out_size; (void)ws_size;
  const float* inputs = (const float*)d_in[0];   // [70,256,850]
  const float* h0in   = (const float*)d_in[1];   // [1,256,850]
  const float* W0     = (const float*)d_in[2];   // [1700,1700]
  const float* Ws     = (const float*)d_in[3];   // [8,850,1700]
  float* out = (float*)d_out;                    // [70*256*850 + 256*850]

  float* S[9];
  for (int i = 0; i < 9; ++i) S[i] = (float*)d_ws + (size_t)i * SSZ;

  const dim3 blk(256);
  const dim3 g1(4, 14, 1), g2(4, 14, 2), g3(4, 14, 3);

  for (int t = 0; t < 70; ++t) {
    const float* xt = inputs + (size_t)t * SSZ;
    const float* hp = (t == 0) ? h0in : out + (size_t)(t - 1) * SSZ;

    // s0 = hp + sig(c0)*(tanh(h0)-hp),  [x|hp] @ W0, K=1700
    { EdgeB3 b{}; b.e[0] = {xt, hp, W0, hp, S[0], 1700, 0};
      k_gemm_gate<<<g1, blk, 0, stream>>>(b); }
    // L1: e0 (tanh, pred s0)
    { EdgeB3 b{}; b.e[0] = {S[0], S[0], Ws + 0 * WSTRIDE, S[0], S[1], 850, 0};
      k_gemm_gate<<<g1, blk, 0, stream>>>(b); }
    // L2: e1 (relu, s1), e2 (relu, s1), e3 (identity, s1)
    { EdgeB3 b{};
      b.e[0] = {S[1], S[1], Ws + 1 * WSTRIDE, S[1], S[2], 850, 1};
      b.e[1] = {S[1], S[1], Ws + 2 * WSTRIDE, S[1], S[3], 850, 1};
      b.e[2] = {S[1], S[1], Ws + 3 * WSTRIDE, S[1], S[4], 850, 3};
      k_gemm_gate<<<g3, blk, 0, stream>>>(b); }
    // L3: e4 (tanh, s2) -> s5 ; e6 (tanh, s3) -> s7
    { EdgeB3 b{};
      b.e[0] = {S[2], S[2], Ws + 4 * WSTRIDE, S[2], S[5], 850, 0};
      b.e[1] = {S[3], S[3], Ws + 6 * WSTRIDE, S[3], S[7], 850, 0};
      k_gemm_gate<<<g2, blk, 0, stream>>>(b); }
    // L4: e5 (sigmoid, s5) -> s6 ; e7 (relu, s5) -> s8
    { EdgeB3 b{};
      b.e[0] = {S[5], S[5], Ws + 5 * WSTRIDE, S[5], S[6], 850, 2};
      b.e[1] = {S[5], S[5], Ws + 7 * WSTRIDE, S[5], S[8], 850, 1};
      k_gemm_gate<<<g2, blk, 0, stream>>>(b); }
    // h_new = mean(s1..s8) -> hiddens[t]  (+ final-hidden tail at t=69)
    float* o2 = (t == 69) ? (out + (size_t)70 * SSZ) : nullptr;
    k_mean8<<<dim3((SSZ / 4 + 255) / 256), blk, 0, stream>>>(
        S[1], S[2], S[3], S[4], S[5], S[6], S[7], S[8],
        out + (size_t)t * SSZ, o2);
  }
}

// Round 3
// 20099.208 us; speedup vs baseline: 1.8061x; 1.8061x over previous
//
#include <hip/hip_runtime.h>
#include <math.h>

#define NHD 850
#define SSZ (256 * 850)
#define KP0 1728                 // K=1700 padded to 32
#define KP1 864                  // K=850 padded to 32
#define WES ((size_t)1700 * KP1) // elements per transposed edge weight

typedef float f32x4 __attribute__((ext_vector_type(4)));
typedef short short8 __attribute__((ext_vector_type(8)));

__device__ __forceinline__ unsigned short f2bf(float x) {
  unsigned u = __float_as_uint(x);
  u += 0x7fff + ((u >> 16) & 1);           // RNE
  return (unsigned short)(u >> 16);
}
__device__ __forceinline__ float bf2f(unsigned short b) {
  return __uint_as_float(((unsigned)b) << 16);
}
__device__ __forceinline__ float sigf(float x) { return 1.0f / (1.0f + expf(-x)); }
__device__ __forceinline__ float actf(int a, float x) {
  switch (a) {
    case 0: return tanhf(x);
    case 1: return fmaxf(x, 0.0f);
    case 2: return sigf(x);
    default: return x;
  }
}

// ---------------- weight split+transpose: in[K][N] fp32 -> out_hi/lo [N][KPad] bf16
struct TransCfg {
  const float* in; unsigned short* oh; unsigned short* ol;
  long inStride, outStride;     // per-blockIdx.z element strides
  int K, N, KPad;
};

__global__ __launch_bounds__(256) void k_wsplit(TransCfg c) {
  const float* in = c.in + (size_t)blockIdx.z * c.inStride;
  unsigned short* oh = c.oh + (size_t)blockIdx.z * c.outStride;
  unsigned short* ol = c.ol + (size_t)blockIdx.z * c.outStride;
  __shared__ float tile[32][33];
  const int tx = threadIdx.x, ty = threadIdx.y;       // (32,8)
  const int k0 = blockIdx.x * 32, n0 = blockIdx.y * 32;
  #pragma unroll
  for (int i = 0; i < 4; ++i) {
    int k = k0 + ty + i * 8, n = n0 + tx;
    tile[ty + i * 8][tx] = (k < c.K && n < c.N) ? in[(size_t)k * c.N + n] : 0.f;
  }
  __syncthreads();
  #pragma unroll
  for (int i = 0; i < 4; ++i) {
    int n = n0 + ty + i * 8, k = k0 + tx;
    if (n < c.N && k < c.KPad) {
      float v = tile[tx][ty + i * 8];
      unsigned short h = f2bf(v);
      oh[(size_t)n * c.KPad + k] = h;
      ol[(size_t)n * c.KPad + k] = f2bf(v - bf2f(h));
    }
  }
}

// ---------------- fused GEMM + highway gate (bf16x2, 3-term MFMA)
struct GemmCfg {
  const float* Ax; const float* Ah;            // A: k<850 from Ax, k>=850 from Ah
  const unsigned short* Wh; const unsigned short* Wl;  // transposed [1700][KPad]
  const float* pred; float* Sout;
  int K, KPad, act;
};
struct GemmB3 { GemmCfg e[3]; };

#define MFMA(a, b, c) __builtin_amdgcn_mfma_f32_16x16x32_bf16(a, b, c, 0, 0, 0)

__global__ __launch_bounds__(256) void k_gemm_gate(GemmB3 bb) {
  const GemmCfg cfg = bb.e[blockIdx.z];
  const int row0 = (blockIdx.x / 14) * 64;
  const int col0 = (blockIdx.x % 14) * 64;
  __shared__ __align__(16) unsigned short sA[2][64][40];      // [prec][row][k] pad->80B rows
  __shared__ __align__(16) unsigned short sW[2][2][64][40];   // [c/h][prec][col][k]
  const int tid = threadIdx.x;
  const int K = cfg.K, KPad = cfg.KPad;
  const int lim = (K < NHD) ? K : NHD;
  const int ar = tid >> 2, a8 = (tid & 3) << 3;   // staging: 64 x (4x8)
  const int lane = tid & 63, wid = tid >> 6;
  const int wr = wid >> 1, wc = wid & 1;          // wave quadrant (2x2)
  const int lrow = lane & 15, lk = (lane >> 4) << 3;

  f32x4 accC[2][2] = {}; f32x4 accH[2][2] = {};

  for (int kt = 0; kt < KPad; kt += 32) {
    // ---- A stage: fp32 -> split bf16 hi/lo
    {
      const int r = row0 + ar, kb = kt + a8;
      float v[8];
      if (kb + 8 <= lim) {
        const float2* p = (const float2*)(cfg.Ax + (size_t)r * NHD + kb);
        float2 x0 = p[0], x1 = p[1], x2 = p[2], x3 = p[3];
        v[0]=x0.x; v[1]=x0.y; v[2]=x1.x; v[3]=x1.y;
        v[4]=x2.x; v[5]=x2.y; v[6]=x3.x; v[7]=x3.y;
      } else if (kb >= NHD && kb + 8 <= K) {
        const float2* p = (const float2*)(cfg.Ah + (size_t)r * NHD + (kb - NHD));
        float2 x0 = p[0], x1 = p[1], x2 = p[2], x3 = p[3];
        v[0]=x0.x; v[1]=x0.y; v[2]=x1.x; v[3]=x1.y;
        v[4]=x2.x; v[5]=x2.y; v[6]=x3.x; v[7]=x3.y;
      } else {
        #pragma unroll
        for (int j = 0; j < 8; ++j) {
          int k = kb + j; float x = 0.f;
          if (k < lim) x = cfg.Ax[(size_t)r * NHD + k];
          else if (k < K) x = cfg.Ah[(size_t)r * NHD + (k - NHD)];
          v[j] = x;
        }
      }
      short8 hi8, lo8;
      #pragma unroll
      for (int j = 0; j < 8; ++j) {
        unsigned short h = f2bf(v[j]);
        hi8[j] = (short)h;
        lo8[j] = (short)f2bf(v[j] - bf2f(h));
      }
      *(short8*)&sA[0][ar][a8] = hi8;
      *(short8*)&sA[1][ar][a8] = lo8;
    }
    // ---- W stage: 16B loads from pre-transposed hi/lo
    {
      const int colw = col0 + ar;
      if (colw < NHD) {
        const size_t oc = (size_t)colw * KPad + kt + a8;
        const size_t oh = (size_t)(NHD + colw) * KPad + kt + a8;
        *(short8*)&sW[0][0][ar][a8] = *(const short8*)(cfg.Wh + oc);
        *(short8*)&sW[0][1][ar][a8] = *(const short8*)(cfg.Wl + oc);
        *(short8*)&sW[1][0][ar][a8] = *(const short8*)(cfg.Wh + oh);
        *(short8*)&sW[1][1][ar][a8] = *(const short8*)(cfg.Wl + oh);
      } else {
        short8 z = {};
        *(short8*)&sW[0][0][ar][a8] = z; *(short8*)&sW[0][1][ar][a8] = z;
        *(short8*)&sW[1][0][ar][a8] = z; *(short8*)&sW[1][1][ar][a8] = z;
      }
    }
    __syncthreads();

    short8 aF0[2], aF1[2];
    #pragma unroll
    for (int rt = 0; rt < 2; ++rt) {
      aF0[rt] = *(const short8*)&sA[0][wr * 32 + rt * 16 + lrow][lk];
      aF1[rt] = *(const short8*)&sA[1][wr * 32 + rt * 16 + lrow][lk];
    }
    #pragma unroll
    for (int ct = 0; ct < 2; ++ct) {
      const int colf = wc * 32 + ct * 16 + lrow;
      short8 cH = *(const short8*)&sW[0][0][colf][lk];
      short8 cL = *(const short8*)&sW[0][1][colf][lk];
      short8 hH = *(const short8*)&sW[1][0][colf][lk];
      short8 hL = *(const short8*)&sW[1][1][colf][lk];
      #pragma unroll
      for (int rt = 0; rt < 2; ++rt) {
        accC[rt][ct] = MFMA(aF0[rt], cH, accC[rt][ct]);
        accC[rt][ct] = MFMA(aF1[rt], cH, accC[rt][ct]);
        accC[rt][ct] = MFMA(aF0[rt], cL, accC[rt][ct]);
        accH[rt][ct] = MFMA(aF0[rt], hH, accH[rt][ct]);
        accH[rt][ct] = MFMA(aF1[rt], hH, accH[rt][ct]);
        accH[rt][ct] = MFMA(aF0[rt], hL, accH[rt][ct]);
      }
    }
    __syncthreads();
  }

  // ---- fused highway-gate epilogue (C/D: col=lane&15, row=(lane>>4)*4+q)
  #pragma unroll
  for (int rt = 0; rt < 2; ++rt)
  #pragma unroll
  for (int ct = 0; ct < 2; ++ct) {
    const int colb = col0 + wc * 32 + ct * 16 + lrow;
    if (colb < NHD) {
      #pragma unroll
      for (int q = 0; q < 4; ++q) {
        const int row = row0 + wr * 32 + rt * 16 + ((lane >> 4) << 2) + q;
        const size_t o = (size_t)row * NHD + colb;
        float p = cfg.pred[o];
        cfg.Sout[o] = p + sigf(accC[rt][ct][q]) * (actf(cfg.act, accH[rt][ct][q]) - p);
      }
    }
  }
}

// ---------------- L4 (e5 sigmoid + e7 relu, pred S5) + mean(s1..s8) fused
struct L4Cfg {
  const float* A;                                        // S5 (= pred)
  const unsigned short* W5h; const unsigned short* W5l;
  const unsigned short* W7h; const unsigned short* W7l;
  const float* S1; const float* S2; const float* S3; const float* S4;
  const float* S7;
  float* ot; float* tail;
};

__global__ __launch_bounds__(256) void k_l4mean(L4Cfg cfg) {
  const int row0 = (blockIdx.x / 14) * 64;
  const int col0 = (blockIdx.x % 14) * 64;
  __shared__ __align__(16) unsigned short sA[2][64][40];
  __shared__ __align__(16) unsigned short sW[2][2][2][64][40]; // [edge][c/h][prec]
  const int tid = threadIdx.x;
  const int ar = tid >> 2, a8 = (tid & 3) << 3;
  const int lane = tid & 63, wid = tid >> 6;
  const int wr = wid >> 1, wc = wid & 1;
  const int lrow = lane & 15, lk = (lane >> 4) << 3;

  f32x4 acc[2][2][2][2] = {};   // [edge][c/h][rt][ct]

  for (int kt = 0; kt < KP1; kt += 32) {
    {
      const int r = row0 + ar, kb = kt + a8;
      float v[8];
      if (kb + 8 <= NHD) {
        const float2* p = (const float2*)(cfg.A + (size_t)r * NHD + kb);
        float2 x0 = p[0], x1 = p[1], x2 = p[2], x3 = p[3];
        v[0]=x0.x; v[1]=x0.y; v[2]=x1.x; v[3]=x1.y;
        v[4]=x2.x; v[5]=x2.y; v[6]=x3.x; v[7]=x3.y;
      } else {
        #pragma unroll
        for (int j = 0; j < 8; ++j) {
          int k = kb + j;
          v[j] = (k < NHD) ? cfg.A[(size_t)r * NHD + k] : 0.f;
        }
      }
      short8 hi8, lo8;
      #pragma unroll
      for (int j = 0; j < 8; ++j) {
        unsigned short h = f2bf(v[j]);
        hi8[j] = (short)h;
        lo8[j] = (short)f2bf(v[j] - bf2f(h));
      }
      *(short8*)&sA[0][ar][a8] = hi8;
      *(short8*)&sA[1][ar][a8] = lo8;
    }
    {
      const int colw = col0 + ar;
      if (colw < NHD) {
        const size_t oc = (size_t)colw * KP1 + kt + a8;
        const size_t oh = (size_t)(NHD + colw) * KP1 + kt + a8;
        *(short8*)&sW[0][0][0][ar][a8] = *(const short8*)(cfg.W5h + oc);
        *(short8*)&sW[0][0][1][ar][a8] = *(const short8*)(cfg.W5l + oc);
        *(short8*)&sW[0][1][0][ar][a8] = *(const short8*)(cfg.W5h + oh);
        *(short8*)&sW[0][1][1][ar][a8] = *(const short8*)(cfg.W5l + oh);
        *(short8*)&sW[1][0][0][ar][a8] = *(const short8*)(cfg.W7h + oc);
        *(short8*)&sW[1][0][1][ar][a8] = *(const short8*)(cfg.W7l + oc);
        *(short8*)&sW[1][1][0][ar][a8] = *(const short8*)(cfg.W7h + oh);
        *(short8*)&sW[1][1][1][ar][a8] = *(const short8*)(cfg.W7l + oh);
      } else {
        short8 z = {};
        #pragma unroll
        for (int e = 0; e < 2; ++e)
        #pragma unroll
        for (int s = 0; s < 2; ++s) {
          *(short8*)&sW[e][s][0][ar][a8] = z;
          *(short8*)&sW[e][s][1][ar][a8] = z;
        }
      }
    }
    __syncthreads();

    short8 aF0[2], aF1[2];
    #pragma unroll
    for (int rt = 0; rt < 2; ++rt) {
      aF0[rt] = *(const short8*)&sA[0][wr * 32 + rt * 16 + lrow][lk];
      aF1[rt] = *(const short8*)&sA[1][wr * 32 + rt * 16 + lrow][lk];
    }
    #pragma unroll
    for (int e = 0; e < 2; ++e)
    #pragma unroll
    for (int ct = 0; ct < 2; ++ct) {
      const int colf = wc * 32 + ct * 16 + lrow;
      short8 cH = *(const short8*)&sW[e][0][0][colf][lk];
      short8 cL = *(const short8*)&sW[e][0][1][colf][lk];
      short8 hH = *(const short8*)&sW[e][1][0][colf][lk];
      short8 hL = *(const short8*)&sW[e][1][1][colf][lk];
      #pragma unroll
      for (int rt = 0; rt < 2; ++rt) {
        acc[e][0][rt][ct] = MFMA(aF0[rt], cH, acc[e][0][rt][ct]);
        acc[e][0][rt][ct] = MFMA(aF1[rt], cH, acc[e][0][rt][ct]);
        acc[e][0][rt][ct] = MFMA(aF0[rt], cL, acc[e][0][rt][ct]);
        acc[e][1][rt][ct] = MFMA(aF0[rt], hH, acc[e][1][rt][ct]);
        acc[e][1][rt][ct] = MFMA(aF1[rt], hH, acc[e][1][rt][ct]);
        acc[e][1][rt][ct] = MFMA(aF0[rt], hL, acc[e][1][rt][ct]);
      }
    }
    __syncthreads();
  }

  #pragma unroll
  for (int rt = 0; rt < 2; ++rt)
  #pragma unroll
  for (int ct = 0; ct < 2; ++ct) {
    const int colb = col0 + wc * 32 + ct * 16 + lrow;
    if (colb < NHD) {
      #pragma unroll
      for (int q = 0; q < 4; ++q) {
        const int row = row0 + wr * 32 + rt * 16 + ((lane >> 4) << 2) + q;
        const size_t o = (size_t)row * NHD + colb;
        float p5 = cfg.A[o];
        float s6 = p5 + sigf(acc[0][0][rt][ct][q]) * (sigf(acc[0][1][rt][ct][q]) - p5);
        float s8 = p5 + sigf(acc[1][0][rt][ct][q]) * (fmaxf(acc[1][1][rt][ct][q], 0.f) - p5);
        float m = (cfg.S1[o] + cfg.S2[o] + cfg.S3[o] + cfg.S4[o] +
                   p5 + s6 + cfg.S7[o] + s8) * 0.125f;
        cfg.ot[o] = m;
        if (cfg.tail) cfg.tail[o] = m;
      }
    }
  }
}

extern "C" void kernel_launch(void* const* d_in, const int* in_sizes, int n_in,
                              void* d_out, int out_size, void* d_ws, size_t ws_size,
                              hipStream_t stream) {
  (void)in_sizes; (void)n_in; (void)out_size; (void)ws_size;
  const float* X  = (const float*)d_in[0];   // [70,256,850]
  const float* H0 = (const float*)d_in[1];   // [1,256,850]
  const float* W0 = (const float*)d_in[2];   // [1700,1700]
  const float* Ws = (const float*)d_in[3];   // [8,850,1700]
  float* out = (float*)d_out;

  char* w = (char*)d_ws;
  float* S = (float*)w;                                   // 8 state slots fp32
  size_t off = (size_t)8 * SSZ * sizeof(float);
  unsigned short* W0h = (unsigned short*)(w + off); off += (size_t)1700 * KP0 * 2;
  unsigned short* W0l = (unsigned short*)(w + off); off += (size_t)1700 * KP0 * 2;
  unsigned short* Wsh = (unsigned short*)(w + off); off += (size_t)8 * WES * 2;
  unsigned short* Wsl = (unsigned short*)(w + off);

  float* S0 = S;           float* S1 = S + 1 * (size_t)SSZ;
  float* S2 = S + 2 * (size_t)SSZ; float* S3 = S + 3 * (size_t)SSZ;
  float* S4 = S + 4 * (size_t)SSZ; float* S5 = S + 5 * (size_t)SSZ;
  float* S7 = S + 7 * (size_t)SSZ;

  // ---- weight split + transpose (every call; ws is re-poisoned by harness)
  { TransCfg c{W0, W0h, W0l, 0, 0, 1700, 1700, KP0};
    k_wsplit<<<dim3(KP0 / 32, 54, 1), dim3(32, 8), 0, stream>>>(c); }
  { TransCfg c{Ws, Wsh, Wsl, (long)850 * 1700, (long)WES, 850, 1700, KP1};
    k_wsplit<<<dim3(KP1 / 32, 54, 8), dim3(32, 8), 0, stream>>>(c); }

  const dim3 blk(256);
  for (int t = 0; t < 70; ++t) {
    const float* xt = X + (size_t)t * SSZ;
    const float* hp = t ? out + (size_t)(t - 1) * SSZ : H0;

    GemmB3 b{};
    // s0: [x|hp] @ W0, K=1700, pred=hp, tanh
    b.e[0] = {xt, hp, W0h, W0l, hp, S0, 1700, KP0, 0};
    k_gemm_gate<<<dim3(56, 1, 1), blk, 0, stream>>>(b);
    // e0: s0 @ Ws[0], pred=s0, tanh
    b.e[0] = {S0, S0, Wsh + 0 * WES, Wsl + 0 * WES, S0, S1, 850, KP1, 0};
    k_gemm_gate<<<dim3(56, 1, 1), blk, 0, stream>>>(b);
    // L2: e1(relu)->S2, e2(relu)->S3, e3(ident)->S4; pred S1
    b.e[0] = {S1, S1, Wsh + 1 * WES, Wsl + 1 * WES, S1, S2, 850, KP1, 1};
    b.e[1] = {S1, S1, Wsh + 2 * WES, Wsl + 2 * WES, S1, S3, 850, KP1, 1};
    b.e[2] = {S1, S1, Wsh + 3 * WES, Wsl + 3 * WES, S1, S4, 850, KP1, 3};
    k_gemm_gate<<<dim3(56, 1, 3), blk, 0, stream>>>(b);
    // L3: e4(tanh, A=S2)->S5 ; e6(tanh, A=S3)->S7
    b.e[0] = {S2, S2, Wsh + 4 * WES, Wsl + 4 * WES, S2, S5, 850, KP1, 0};
    b.e[1] = {S3, S3, Wsh + 6 * WES, Wsl + 6 * WES, S3, S7, 850, KP1, 0};
    k_gemm_gate<<<dim3(56, 1, 2), blk, 0, stream>>>(b);
    // L4 + mean -> out[t] (+tail at t=69)
    L4Cfg c{S5, Wsh + 5 * WES, Wsl + 5 * WES, Wsh + 7 * WES, Wsl + 7 * WES,
            S1, S2, S3, S4, S7, out + (size_t)t * SSZ,
            (t == 69) ? out + (size_t)70 * SSZ : nullptr};
    k_l4mean<<<dim3(56, 1, 1), blk, 0, stream>>>(c);
  }
}

// Round 5
// 8925.752 us; speedup vs baseline: 4.0671x; 2.2518x over previous
//
#include <hip/hip_runtime.h>
#include <math.h>

#define NHD 850
#define LDP 1700
#define SSZ (256 * 850)
#define KP0 1728                     // K=1700 padded to 32
#define KP1 864                      // K=850 padded to 32
#define PSTRIDE ((size_t)(256 * 1700))
#define WES ((size_t)1700 * KP1)     // elems per transposed edge weight
#define SBSZ ((size_t)256 * KP1)     // one bf16 state buffer (padded)

typedef float f32x4 __attribute__((ext_vector_type(4)));
typedef short short8 __attribute__((ext_vector_type(8)));

__device__ __forceinline__ unsigned short f2bf(float x) {
  unsigned u = __float_as_uint(x);
  u += 0x7fff + ((u >> 16) & 1);           // RNE
  return (unsigned short)(u >> 16);
}
__device__ __forceinline__ float bf2f(unsigned short b) {
  return __uint_as_float(((unsigned)b) << 16);
}
__device__ __forceinline__ float sigf(float x) { return 1.0f / (1.0f + expf(-x)); }
__device__ __forceinline__ float actf(int a, float x) {
  switch (a) {
    case 0: return tanhf(x);
    case 1: return fmaxf(x, 0.0f);
    case 2: return sigf(x);
    default: return x;
  }
}

#define MFMA(a, b, c) __builtin_amdgcn_mfma_f32_16x16x32_bf16(a, b, c, 0, 0, 0)

// ---------------- weight split+transpose: in[K][N] fp32 -> hi/lo [N][KPad] bf16
struct TransCfg {
  const float* in; unsigned short* oh; unsigned short* ol;
  long inStride, outStride;
  int K, N, KPad;
};

__global__ __launch_bounds__(256) void k_wsplit(TransCfg c) {
  const float* in = c.in + (size_t)blockIdx.z * c.inStride;
  unsigned short* oh = c.oh + (size_t)blockIdx.z * c.outStride;
  unsigned short* ol = c.ol + (size_t)blockIdx.z * c.outStride;
  __shared__ float tile[32][33];
  const int tx = threadIdx.x, ty = threadIdx.y;       // (32,8)
  const int k0 = blockIdx.x * 32, n0 = blockIdx.y * 32;
  #pragma unroll
  for (int i = 0; i < 4; ++i) {
    int k = k0 + ty + i * 8, n = n0 + tx;
    tile[ty + i * 8][tx] = (k < c.K && n < c.N) ? in[(size_t)k * c.N + n] : 0.f;
  }
  __syncthreads();
  #pragma unroll
  for (int i = 0; i < 4; ++i) {
    int n = n0 + ty + i * 8, k = k0 + tx;
    if (n < c.N && k < c.KPad) {
      float v = tile[tx][ty + i * 8];
      unsigned short h = f2bf(v);
      oh[(size_t)n * c.KPad + k] = h;
      ol[(size_t)n * c.KPad + k] = f2bf(v - bf2f(h));
    }
  }
}

// ---------------- edge GEMM, split-K partials (A pre-split bf16 hi/lo)
struct GEdge {
  const unsigned short* Ahi; const unsigned short* Alo;   // [256][KP1]
  const unsigned short* Wh;  const unsigned short* Wl;    // [1700][KP1]
  int ps;                                                  // partial base idx
};
struct GemmArgs { GEdge e[3]; float* P; int nIter; };

__global__ __launch_bounds__(256) void k_gemm_bf(GemmArgs ga) {
  const GEdge eg = ga.e[blockIdx.z];
  const int per = (ga.nIter + gridDim.y - 1) / gridDim.y;
  const int i0 = blockIdx.y * per;
  const int i1 = min(ga.nIter, i0 + per);
  float* __restrict__ P = ga.P + (size_t)(eg.ps + blockIdx.y) * PSTRIDE;

  const int row0 = (blockIdx.x / 14) * 64;
  const int col0 = (blockIdx.x % 14) * 64;
  __shared__ __align__(16) unsigned short sA[2][64][40];
  __shared__ __align__(16) unsigned short sW[2][2][64][40];
  const int tid = threadIdx.x;
  const int ar = tid >> 2, a8 = (tid & 3) << 3;
  const int lane = tid & 63, wid = tid >> 6;
  const int wr = wid >> 1, wc = wid & 1;
  const int lrow = lane & 15, lk = (lane >> 4) << 3;

  f32x4 accC[2][2] = {}; f32x4 accH[2][2] = {};

  for (int it = i0; it < i1; ++it) {
    const int kt = it * 32;
    {
      const size_t o = (size_t)(row0 + ar) * KP1 + kt + a8;
      *(short8*)&sA[0][ar][a8] = *(const short8*)(eg.Ahi + o);
      *(short8*)&sA[1][ar][a8] = *(const short8*)(eg.Alo + o);
    }
    {
      const int colw = col0 + ar;
      if (colw < NHD) {
        const size_t oc = (size_t)colw * KP1 + kt + a8;
        const size_t oh = (size_t)(NHD + colw) * KP1 + kt + a8;
        *(short8*)&sW[0][0][ar][a8] = *(const short8*)(eg.Wh + oc);
        *(short8*)&sW[0][1][ar][a8] = *(const short8*)(eg.Wl + oc);
        *(short8*)&sW[1][0][ar][a8] = *(const short8*)(eg.Wh + oh);
        *(short8*)&sW[1][1][ar][a8] = *(const short8*)(eg.Wl + oh);
      } else {
        short8 z = {};
        *(short8*)&sW[0][0][ar][a8] = z; *(short8*)&sW[0][1][ar][a8] = z;
        *(short8*)&sW[1][0][ar][a8] = z; *(short8*)&sW[1][1][ar][a8] = z;
      }
    }
    __syncthreads();

    short8 aF0[2], aF1[2];
    #pragma unroll
    for (int rt = 0; rt < 2; ++rt) {
      aF0[rt] = *(const short8*)&sA[0][wr * 32 + rt * 16 + lrow][lk];
      aF1[rt] = *(const short8*)&sA[1][wr * 32 + rt * 16 + lrow][lk];
    }
    #pragma unroll
    for (int ct = 0; ct < 2; ++ct) {
      const int colf = wc * 32 + ct * 16 + lrow;
      short8 cH = *(const short8*)&sW[0][0][colf][lk];
      short8 cL = *(const short8*)&sW[0][1][colf][lk];
      short8 hH = *(const short8*)&sW[1][0][colf][lk];
      short8 hL = *(const short8*)&sW[1][1][colf][lk];
      #pragma unroll
      for (int rt = 0; rt < 2; ++rt) {
        accC[rt][ct] = MFMA(aF0[rt], cH, accC[rt][ct]);
        accC[rt][ct] = MFMA(aF1[rt], cH, accC[rt][ct]);
        accC[rt][ct] = MFMA(aF0[rt], cL, accC[rt][ct]);
        accH[rt][ct] = MFMA(aF0[rt], hH, accH[rt][ct]);
        accH[rt][ct] = MFMA(aF1[rt], hH, accH[rt][ct]);
        accH[rt][ct] = MFMA(aF0[rt], hL, accH[rt][ct]);
      }
    }
    __syncthreads();
  }

  #pragma unroll
  for (int rt = 0; rt < 2; ++rt)
  #pragma unroll
  for (int ct = 0; ct < 2; ++ct) {
    const int colb = col0 + wc * 32 + ct * 16 + lrow;
    if (colb < NHD) {
      #pragma unroll
      for (int q = 0; q < 4; ++q) {
        const int row = row0 + wr * 32 + rt * 16 + ((lane >> 4) << 2) + q;
        P[(size_t)row * LDP + colb]       = accC[rt][ct][q];
        P[(size_t)row * LDP + NHD + colb] = accH[rt][ct][q];
      }
    }
  }
}

// ---------------- s0 GEMM (A = [x | h] fp32, split on the fly), split-K partials
struct S0Args {
  const float* X; const float* H;
  const unsigned short* Wh; const unsigned short* Wl;    // [1700][KP0]
  float* P; int nIter;
};

__global__ __launch_bounds__(256) void k_gemm_s0(S0Args ga) {
  const int per = (ga.nIter + gridDim.y - 1) / gridDim.y;
  const int i0 = blockIdx.y * per;
  const int i1 = min(ga.nIter, i0 + per);
  float* __restrict__ P = ga.P + (size_t)blockIdx.y * PSTRIDE;

  const int row0 = (blockIdx.x / 14) * 64;
  const int col0 = (blockIdx.x % 14) * 64;
  __shared__ __align__(16) unsigned short sA[2][64][40];
  __shared__ __align__(16) unsigned short sW[2][2][64][40];
  const int tid = threadIdx.x;
  const int ar = tid >> 2, a8 = (tid & 3) << 3;
  const int lane = tid & 63, wid = tid >> 6;
  const int wr = wid >> 1, wc = wid & 1;
  const int lrow = lane & 15, lk = (lane >> 4) << 3;

  f32x4 accC[2][2] = {}; f32x4 accH[2][2] = {};

  for (int it = i0; it < i1; ++it) {
    const int kt = it * 32;
    {
      const int r = row0 + ar, kb = kt + a8;
      float v[8];
      if (kb + 8 <= NHD) {
        const float2* p = (const float2*)(ga.X + (size_t)r * NHD + kb);
        float2 x0 = p[0], x1 = p[1], x2 = p[2], x3 = p[3];
        v[0]=x0.x; v[1]=x0.y; v[2]=x1.x; v[3]=x1.y;
        v[4]=x2.x; v[5]=x2.y; v[6]=x3.x; v[7]=x3.y;
      } else if (kb >= NHD && kb + 8 <= 1700) {
        const float2* p = (const float2*)(ga.H + (size_t)r * NHD + (kb - NHD));
        float2 x0 = p[0], x1 = p[1], x2 = p[2], x3 = p[3];
        v[0]=x0.x; v[1]=x0.y; v[2]=x1.x; v[3]=x1.y;
        v[4]=x2.x; v[5]=x2.y; v[6]=x3.x; v[7]=x3.y;
      } else {
        #pragma unroll
        for (int j = 0; j < 8; ++j) {
          int k = kb + j; float x = 0.f;
          if (k < NHD) x = ga.X[(size_t)r * NHD + k];
          else if (k < 1700) x = ga.H[(size_t)r * NHD + (k - NHD)];
          v[j] = x;
        }
      }
      short8 hi8, lo8;
      #pragma unroll
      for (int j = 0; j < 8; ++j) {
        unsigned short h = f2bf(v[j]);
        hi8[j] = (short)h;
        lo8[j] = (short)f2bf(v[j] - bf2f(h));
      }
      *(short8*)&sA[0][ar][a8] = hi8;
      *(short8*)&sA[1][ar][a8] = lo8;
    }
    {
      const int colw = col0 + ar;
      if (colw < NHD) {
        const size_t oc = (size_t)colw * KP0 + kt + a8;
        const size_t oh = (size_t)(NHD + colw) * KP0 + kt + a8;
        *(short8*)&sW[0][0][ar][a8] = *(const short8*)(ga.Wh + oc);
        *(short8*)&sW[0][1][ar][a8] = *(const short8*)(ga.Wl + oc);
        *(short8*)&sW[1][0][ar][a8] = *(const short8*)(ga.Wh + oh);
        *(short8*)&sW[1][1][ar][a8] = *(const short8*)(ga.Wl + oh);
      } else {
        short8 z = {};
        *(short8*)&sW[0][0][ar][a8] = z; *(short8*)&sW[0][1][ar][a8] = z;
        *(short8*)&sW[1][0][ar][a8] = z; *(short8*)&sW[1][1][ar][a8] = z;
      }
    }
    __syncthreads();

    short8 aF0[2], aF1[2];
    #pragma unroll
    for (int rt = 0; rt < 2; ++rt) {
      aF0[rt] = *(const short8*)&sA[0][wr * 32 + rt * 16 + lrow][lk];
      aF1[rt] = *(const short8*)&sA[1][wr * 32 + rt * 16 + lrow][lk];
    }
    #pragma unroll
    for (int ct = 0; ct < 2; ++ct) {
      const int colf = wc * 32 + ct * 16 + lrow;
      short8 cH = *(const short8*)&sW[0][0][colf][lk];
      short8 cL = *(const short8*)&sW[0][1][colf][lk];
      short8 hH = *(const short8*)&sW[1][0][colf][lk];
      short8 hL = *(const short8*)&sW[1][1][colf][lk];
      #pragma unroll
      for (int rt = 0; rt < 2; ++rt) {
        accC[rt][ct] = MFMA(aF0[rt], cH, accC[rt][ct]);
        accC[rt][ct] = MFMA(aF1[rt], cH, accC[rt][ct]);
        accC[rt][ct] = MFMA(aF0[rt], cL, accC[rt][ct]);
        accH[rt][ct] = MFMA(aF0[rt], hH, accH[rt][ct]);
        accH[rt][ct] = MFMA(aF1[rt], hH, accH[rt][ct]);
        accH[rt][ct] = MFMA(aF0[rt], hL, accH[rt][ct]);
      }
    }
    __syncthreads();
  }

  #pragma unroll
  for (int rt = 0; rt < 2; ++rt)
  #pragma unroll
  for (int ct = 0; ct < 2; ++ct) {
    const int colb = col0 + wc * 32 + ct * 16 + lrow;
    if (colb < NHD) {
      #pragma unroll
      for (int q = 0; q < 4; ++q) {
        const int row = row0 + wr * 32 + rt * 16 + ((lane >> 4) << 2) + q;
        P[(size_t)row * LDP + colb]       = accC[rt][ct][q];
        P[(size_t)row * LDP + NHD + colb] = accH[rt][ct][q];
      }
    }
  }
}

// ---------------- gate: sum partials, highway gate, write fp32 + bf16 hi/lo
struct GateEdge {
  const float* P; const float* pred; float* Sf;
  unsigned short* Shi; unsigned short* Slo;
  int nsplit; int act;
};
struct GateArgs { GateEdge e[3]; };

__global__ __launch_bounds__(256) void k_gate(GateArgs ga) {
  const GateEdge e = ga.e[blockIdx.z];
  const int id = blockIdx.x * 256 + threadIdx.x;     // 0 .. 256*432-1
  const int r = id / 432, cp = id - r * 432;
  const int c = cp * 2;
  if (c >= NHD) {                                    // zero the K-pad columns
    if (e.Shi) {
      *(unsigned*)&e.Shi[(size_t)r * KP1 + c] = 0;
      *(unsigned*)&e.Slo[(size_t)r * KP1 + c] = 0;
    }
    return;
  }
  const size_t pb = (size_t)r * LDP + c;
  float2 cv = *(const float2*)(e.P + pb);
  float2 hv = *(const float2*)(e.P + pb + NHD);
  for (int s = 1; s < e.nsplit; ++s) {
    float2 a = *(const float2*)(e.P + (size_t)s * PSTRIDE + pb);
    float2 b = *(const float2*)(e.P + (size_t)s * PSTRIDE + pb + NHD);
    cv.x += a.x; cv.y += a.y; hv.x += b.x; hv.y += b.y;
  }
  const size_t oo = (size_t)r * NHD + c;
  float2 pv = *(const float2*)(e.pred + oo);
  float2 o;
  o.x = pv.x + sigf(cv.x) * (actf(e.act, hv.x) - pv.x);
  o.y = pv.y + sigf(cv.y) * (actf(e.act, hv.y) - pv.y);
  *(float2*)(e.Sf + oo) = o;
  if (e.Shi) {
    unsigned short hx = f2bf(o.x), hy = f2bf(o.y);
    unsigned short lx = f2bf(o.x - bf2f(hx)), ly = f2bf(o.y - bf2f(hy));
    *(unsigned*)&e.Shi[(size_t)r * KP1 + c] = (unsigned)hx | ((unsigned)hy << 16);
    *(unsigned*)&e.Slo[(size_t)r * KP1 + c] = (unsigned)lx | ((unsigned)ly << 16);
  }
}

// ---------------- final: gate e5 (sigmoid) + e7 (relu), pred S5; mean -> out
struct FinArgs {
  const float* P;
  const float* S1; const float* S2; const float* S3; const float* S4;
  const float* S5; const float* S7;
  float* ot; float* tail;
};

__global__ __launch_bounds__(256) void k_fin(FinArgs f) {
  const int id = blockIdx.x * 256 + threadIdx.x;     // 0 .. 256*425-1
  const int r = id / 425, cp = id - r * 425;
  const int c = cp * 2;
  const size_t pb = (size_t)r * LDP + c;
  float2 c5 = *(const float2*)(f.P + pb);
  float2 h5 = *(const float2*)(f.P + pb + NHD);
  { float2 a = *(const float2*)(f.P + PSTRIDE + pb);
    float2 b = *(const float2*)(f.P + PSTRIDE + pb + NHD);
    c5.x += a.x; c5.y += a.y; h5.x += b.x; h5.y += b.y; }
  float2 c7 = *(const float2*)(f.P + 2 * PSTRIDE + pb);
  float2 h7 = *(const float2*)(f.P + 2 * PSTRIDE + pb + NHD);
  { float2 a = *(const float2*)(f.P + 3 * PSTRIDE + pb);
    float2 b = *(const float2*)(f.P + 3 * PSTRIDE + pb + NHD);
    c7.x += a.x; c7.y += a.y; h7.x += b.x; h7.y += b.y; }
  const size_t oo = (size_t)r * NHD + c;
  float2 p5 = *(const float2*)(f.S5 + oo);
  float2 s6, s8;
  s6.x = p5.x + sigf(c5.x) * (sigf(h5.x) - p5.x);
  s6.y = p5.y + sigf(c5.y) * (sigf(h5.y) - p5.y);
  s8.x = p5.x + sigf(c7.x) * (fmaxf(h7.x, 0.f) - p5.x);
  s8.y = p5.y + sigf(c7.y) * (fmaxf(h7.y, 0.f) - p5.y);
  float2 v1 = *(const float2*)(f.S1 + oo), v2 = *(const float2*)(f.S2 + oo);
  float2 v3 = *(const float2*)(f.S3 + oo), v4 = *(const float2*)(f.S4 + oo);
  float2 v7 = *(const float2*)(f.S7 + oo);
  float2 m;
  m.x = (v1.x + v2.x + v3.x + v4.x + p5.x + s6.x + v7.x + s8.x) * 0.125f;
  m.y = (v1.y + v2.y + v3.y + v4.y + p5.y + s6.y + v7.y + s8.y) * 0.125f;
  *(float2*)(f.ot + oo) = m;
  if (f.tail) *(float2*)(f.tail + oo) = m;
}

extern "C" void kernel_launch(void* const* d_in, const int* in_sizes, int n_in,
                              void* d_out, int out_size, void* d_ws, size_t ws_size,
                              hipStream_t stream) {
  (void)in_sizes; (void)n_in; (void)out_size; (void)ws_size;
  const float* X  = (const float*)d_in[0];
  const float* H0 = (const float*)d_in[1];
  const float* W0 = (const float*)d_in[2];
  const float* Ws = (const float*)d_in[3];
  float* out = (float*)d_out;

  char* w = (char*)d_ws;
  float* Sf = (float*)w;
  size_t off = (size_t)8 * SSZ * sizeof(float);
  unsigned short* Shi = (unsigned short*)(w + off); off += 6 * SBSZ * 2;
  unsigned short* Slo = (unsigned short*)(w + off); off += 6 * SBSZ * 2;
  unsigned short* W0h = (unsigned short*)(w + off); off += (size_t)1700 * KP0 * 2;
  unsigned short* W0l = (unsigned short*)(w + off); off += (size_t)1700 * KP0 * 2;
  unsigned short* Wsh = (unsigned short*)(w + off); off += (size_t)8 * WES * 2;
  unsigned short* Wsl = (unsigned short*)(w + off); off += (size_t)8 * WES * 2;
  float* P = (float*)(w + off);

  auto sf = [&](int i) { return Sf + (size_t)i * SSZ; };
  auto hi = [&](int i) { return Shi + (size_t)i * SBSZ; };
  auto lo = [&](int i) { return Slo + (size_t)i * SBSZ; };

  { TransCfg c{W0, W0h, W0l, 0, 0, 1700, 1700, KP0};
    k_wsplit<<<dim3(KP0 / 32, 54, 1), dim3(32, 8), 0, stream>>>(c); }
  { TransCfg c{Ws, Wsh, Wsl, (long)850 * 1700, (long)WES, 850, 1700, KP1};
    k_wsplit<<<dim3(KP1 / 32, 54, 8), dim3(32, 8), 0, stream>>>(c); }

  const dim3 blk(256);
  for (int t = 0; t < 70; ++t) {
    const float* xt = X + (size_t)t * SSZ;
    const float* hp = t ? out + (size_t)(t - 1) * SSZ : H0;

    // s0: [x|h] @ W0, K=1700, split-K x8
    { S0Args a{xt, hp, W0h, W0l, P, 54};
      k_gemm_s0<<<dim3(56, 8, 1), blk, 0, stream>>>(a); }
    { GateArgs g{}; g.e[0] = {P, hp, sf(0), hi(0), lo(0), 8, 0};
      k_gate<<<dim3(432, 1, 1), blk, 0, stream>>>(g); }

    // e0: s0 @ Ws[0], split-K x4
    { GemmArgs b{}; b.P = P; b.nIter = 27;
      b.e[0] = {hi(0), lo(0), Wsh + 0 * WES, Wsl + 0 * WES, 0};
      k_gemm_bf<<<dim3(56, 4, 1), blk, 0, stream>>>(b); }
    { GateArgs g{}; g.e[0] = {P, sf(0), sf(1), hi(1), lo(1), 4, 0};
      k_gate<<<dim3(432, 1, 1), blk, 0, stream>>>(g); }

    // L2: e1,e2,e3 (A=S1), split-K x2 each
    { GemmArgs b{}; b.P = P; b.nIter = 27;
      b.e[0] = {hi(1), lo(1), Wsh + 1 * WES, Wsl + 1 * WES, 0};
      b.e[1] = {hi(1), lo(1), Wsh + 2 * WES, Wsl + 2 * WES, 2};
      b.e[2] = {hi(1), lo(1), Wsh + 3 * WES, Wsl + 3 * WES, 4};
      k_gemm_bf<<<dim3(56, 2, 3), blk, 0, stream>>>(b); }
    { GateArgs g{};
      g.e[0] = {P,               sf(1), sf(2), hi(2), lo(2), 2, 1};
      g.e[1] = {P + 2 * PSTRIDE, sf(1), sf(3), hi(3), lo(3), 2, 1};
      g.e[2] = {P + 4 * PSTRIDE, sf(1), sf(4), nullptr, nullptr, 2, 3};
      k_gate<<<dim3(432, 1, 3), blk, 0, stream>>>(g); }

    // L3: e4 (A=S2), e6 (A=S3), split-K x2
    { GemmArgs b{}; b.P = P; b.nIter = 27;
      b.e[0] = {hi(2), lo(2), Wsh + 4 * WES, Wsl + 4 * WES, 0};
      b.e[1] = {hi(3), lo(3), Wsh + 6 * WES, Wsl + 6 * WES, 2};
      k_gemm_bf<<<dim3(56, 2, 2), blk, 0, stream>>>(b); }
    { GateArgs g{};
      g.e[0] = {P,               sf(2), sf(5), hi(5), lo(5), 2, 0};
      g.e[1] = {P + 2 * PSTRIDE, sf(3), sf(7), nullptr, nullptr, 2, 0};
      k_gate<<<dim3(432, 1, 2), blk, 0, stream>>>(g); }

    // L4: e5, e7 (A=S5), split-K x2
    { GemmArgs b{}; b.P = P; b.nIter = 27;
      b.e[0] = {hi(5), lo(5), Wsh + 5 * WES, Wsl + 5 * WES, 0};
      b.e[1] = {hi(5), lo(5), Wsh + 7 * WES, Wsl + 7 * WES, 2};
      k_gemm_bf<<<dim3(56, 2, 2), blk, 0, stream>>>(b); }

    // final gate + mean -> out[t] (+ tail at t=69)
    { FinArgs f{P, sf(1), sf(2), sf(3), sf(4), sf(5), sf(7),
                out + (size_t)t * SSZ,
                (t == 69) ? out + (size_t)70 * SSZ : nullptr};
      k_fin<<<dim3(425, 1, 1), blk, 0, stream>>>(f); }
  }
}